// Round 12
// baseline (93.102 us; speedup 1.0000x reference)
//
#include <hip/hip_runtime.h>
#include <hip/hip_bf16.h>

#define D_DIM 1024
#define L_DIM 8
#define T_DIM 2048
#define B_DIM 4
#define TOKS  (B_DIM * T_DIM)                 // 8192
#define OUT_ELEMS ((size_t)TOKS * D_DIM)      // 8388608
#define EPSF 1e-6f
#define PSTRIDE ((size_t)T_DIM * D_DIM)

typedef __attribute__((ext_vector_type(8)))  short short8_t;
typedef __attribute__((ext_vector_type(16))) float f32x16_t;
typedef __attribute__((ext_vector_type(4)))  float f32x4_t;

__device__ __forceinline__ float dot4v(const f32x4_t& a, const f32x4_t& b) {
    return a.x * b.x + a.y * b.y + a.z * b.z + a.w * b.w;
}

__device__ __forceinline__ unsigned short f2bf(float f) {
    union { __hip_bfloat16 h; unsigned short u; } x;
    x.h = __float2bfloat16(f);
    return x.u;
}

__device__ __forceinline__ float bf2f(unsigned short u) {
    union { unsigned int i; float f; } x;
    x.i = ((unsigned int)u) << 16;
    return x.f;
}

__device__ __forceinline__ float lo2f(unsigned int u) {
    union { unsigned int i; float f; } x;
    x.i = u << 16;
    return x.f;
}

__device__ __forceinline__ float hi2f(unsigned int u) {
    union { unsigned int i; float f; } x;
    x.i = u & 0xffff0000u;
    return x.f;
}

#define ISSUE(BUF, PTR) { const float* _p = (PTR);        \
    BUF[0] = *(const f32x4_t*)(_p);                       \
    BUF[1] = *(const f32x4_t*)(_p + 256);                 \
    BUF[2] = *(const f32x4_t*)(_p + 512);                 \
    BUF[3] = *(const f32x4_t*)(_p + 768); }

#define PACK2(x, y) ((unsigned int)f2bf(x) | ((unsigned int)f2bf(y) << 16))

#define PROC(S, BUF) {                                                        \
    float _s = dot4v(BUF[0],BUF[0]) + dot4v(BUF[1],BUF[1])                    \
             + dot4v(BUF[2],BUF[2]) + dot4v(BUF[3],BUF[3]);                   \
    float _d = dot4v(BUF[0],qv[0]) + dot4v(BUF[1],qv[1])                      \
             + dot4v(BUF[2],qv[2]) + dot4v(BUF[3],qv[3]);                     \
    ss[S] = _s; dt[S] = _d;                                                   \
    pw[S][0]=PACK2(BUF[0].x,BUF[0].y); pw[S][1]=PACK2(BUF[0].z,BUF[0].w);     \
    pw[S][2]=PACK2(BUF[1].x,BUF[1].y); pw[S][3]=PACK2(BUF[1].z,BUF[1].w);     \
    pw[S][4]=PACK2(BUF[2].x,BUF[2].y); pw[S][5]=PACK2(BUF[2].z,BUF[2].w);     \
    pw[S][6]=PACK2(BUF[3].x,BUF[3].y); pw[S][7]=PACK2(BUF[3].z,BUF[3].w); }

// ---------------------------------------------------------------------------
// Single fused kernel. 256 blocks x 512 threads; block = 32 tokens.
// Phase A: q tile via MFMA GEMM1/GEMM2 -> qt LDS (bf16), inline weight cvt.
// Phase B: wave-per-token x4, zero barriers, CONTINUOUS-ISSUE row pipeline:
//   double-buffered 4KB row loads (issue l+1 || process l), bf16 row pack,
//   cross-token prefetch so the softmax/delta tail overlaps a load.
// ---------------------------------------------------------------------------
__global__ __launch_bounds__(512) void k_all(const float* __restrict__ h,
                                             const float* __restrict__ prev,
                                             const float* __restrict__ query,
                                             const float* __restrict__ score_w,
                                             const float* __restrict__ out_w,
                                             const float* __restrict__ tg_w,
                                             const float* __restrict__ gate,
                                             const float* __restrict__ tg_b,
                                             const float* __restrict__ qnw,
                                             const float* __restrict__ Wd,
                                             const float* __restrict__ Wu,
                                             float* __restrict__ out,
                                             float* __restrict__ alpha_out) {
    __shared__ __align__(16) char smem[65536];                 // c_red | qt overlay
    float (*c_red)[2][16][64] = (float (*)[2][16][64])smem;    // 64 KB
    unsigned short* qt = (unsigned short*)smem;                // 32 x 1024 bf16

    __shared__ float ssq_red[8][32];
    __shared__ float scale_sh[32];
    __shared__ unsigned short r_sw[2048];

    int tid  = threadIdx.x;
    int w    = tid >> 6;
    int lane = tid & 63;
    int t0   = blockIdx.x * 32;

    // ================= Phase A: GEMM1 =================
    f32x16_t acc0, acc1;
#pragma unroll
    for (int r = 0; r < 16; ++r) { acc0[r] = 0.f; acc1[r] = 0.f; }

    int arow = lane & 31;
    int koff = w * 128 + (lane >> 5) * 8;
    const float* hrow = h + (size_t)(t0 + arow) * D_DIM + koff;
    const float* w0r  = Wd + (size_t)arow * D_DIM + koff;
    const float* w1r  = Wd + (size_t)(32 + arow) * D_DIM + koff;
    const float* nr   = qnw + koff;

    float ssqa = 0.f;
#pragma unroll
    for (int s = 0; s < 8; ++s) {
        f32x4_t ha = *(const f32x4_t*)(hrow + s * 16);
        f32x4_t hb = *(const f32x4_t*)(hrow + s * 16 + 4);
        ssqa += dot4v(ha, ha) + dot4v(hb, hb);
        short8_t af;
        af[0] = (short)f2bf(ha.x); af[1] = (short)f2bf(ha.y);
        af[2] = (short)f2bf(ha.z); af[3] = (short)f2bf(ha.w);
        af[4] = (short)f2bf(hb.x); af[5] = (short)f2bf(hb.y);
        af[6] = (short)f2bf(hb.z); af[7] = (short)f2bf(hb.w);
        f32x4_t na = *(const f32x4_t*)(nr + s * 16);
        f32x4_t nb = *(const f32x4_t*)(nr + s * 16 + 4);
        f32x4_t wa = *(const f32x4_t*)(w0r + s * 16);
        f32x4_t wb = *(const f32x4_t*)(w0r + s * 16 + 4);
        short8_t bf0;
        bf0[0] = (short)f2bf(wa.x * na.x); bf0[1] = (short)f2bf(wa.y * na.y);
        bf0[2] = (short)f2bf(wa.z * na.z); bf0[3] = (short)f2bf(wa.w * na.w);
        bf0[4] = (short)f2bf(wb.x * nb.x); bf0[5] = (short)f2bf(wb.y * nb.y);
        bf0[6] = (short)f2bf(wb.z * nb.z); bf0[7] = (short)f2bf(wb.w * nb.w);
        f32x4_t va = *(const f32x4_t*)(w1r + s * 16);
        f32x4_t vb = *(const f32x4_t*)(w1r + s * 16 + 4);
        short8_t bf1;
        bf1[0] = (short)f2bf(va.x * na.x); bf1[1] = (short)f2bf(va.y * na.y);
        bf1[2] = (short)f2bf(va.z * na.z); bf1[3] = (short)f2bf(va.w * na.w);
        bf1[4] = (short)f2bf(vb.x * nb.x); bf1[5] = (short)f2bf(vb.y * nb.y);
        bf1[6] = (short)f2bf(vb.z * nb.z); bf1[7] = (short)f2bf(vb.w * nb.w);
        acc0 = __builtin_amdgcn_mfma_f32_32x32x16_bf16(af, bf0, acc0, 0, 0, 0);
        acc1 = __builtin_amdgcn_mfma_f32_32x32x16_bf16(af, bf1, acc1, 0, 0, 0);
    }

    ssqa += __shfl_xor(ssqa, 32, 64);
    if (lane < 32) ssq_red[w][lane] = ssqa;
#pragma unroll
    for (int r = 0; r < 16; ++r) {
        c_red[w][0][r][lane] = acc0[r];
        c_red[w][1][r][lane] = acc1[r];
    }
    __syncthreads();

    if (tid < 32) {
        float s8 = 0.f;
#pragma unroll
        for (int u = 0; u < 8; ++u) s8 += ssq_red[u][tid];
        scale_sh[tid] = rsqrtf(s8 * (1.f / D_DIM) + EPSF);
    }
    __syncthreads();

    for (int idx = tid; idx < 2048; idx += 512) {
        int nj = idx >> 10, rem = idx & 1023, reg = rem >> 6, ln = rem & 63;
        float v = 0.f;
#pragma unroll
        for (int u = 0; u < 8; ++u) v += c_red[u][nj][reg][ln];
        int tk = (reg & 3) + 8 * (reg >> 2) + 4 * (ln >> 5);
        int j  = nj * 32 + (ln & 31);
        v *= scale_sh[tk];
        int byte = (tk * 128 + j * 2) ^ ((tk & 7) << 4);
        r_sw[byte >> 1] = f2bf(v);
    }
    __syncthreads();

    // ================= Phase A: GEMM2 -> qt =================
    short8_t afr[4];
#pragma unroll
    for (int s = 0; s < 4; ++s) {
        int tk = lane & 31;
        int k  = s * 16 + (lane >> 5) * 8;
        int byte = (tk * 128 + k * 2) ^ ((tk & 7) << 4);
        afr[s] = *(const short8_t*)(&r_sw[byte >> 1]);
    }
    __syncthreads();   // c_red dead -> qt overlay safe

#pragma unroll
    for (int i = 0; i < 4; ++i) {
        int n0 = (w * 4 + i) * 32;
        int d  = n0 + (lane & 31);
        f32x16_t c;
#pragma unroll
        for (int r = 0; r < 16; ++r) c[r] = 0.f;
        const float* wup = Wu + (size_t)d * 64 + (lane >> 5) * 8;
#pragma unroll
        for (int s = 0; s < 4; ++s) {
            f32x4_t ua = *(const f32x4_t*)(wup + s * 16);
            f32x4_t ub = *(const f32x4_t*)(wup + s * 16 + 4);
            short8_t bf;
            bf[0] = (short)f2bf(ua.x); bf[1] = (short)f2bf(ua.y);
            bf[2] = (short)f2bf(ua.z); bf[3] = (short)f2bf(ua.w);
            bf[4] = (short)f2bf(ub.x); bf[5] = (short)f2bf(ub.y);
            bf[6] = (short)f2bf(ub.z); bf[7] = (short)f2bf(ub.w);
            c = __builtin_amdgcn_mfma_f32_32x32x16_bf16(afr[s], bf, c, 0, 0, 0);
        }
        float qd  = query[d];
        float swd = score_w[d];
#pragma unroll
        for (int r = 0; r < 16; ++r) {
            int tk = (r & 3) + 8 * (r >> 2) + 4 * (lane >> 5);
            unsigned int v = f2bf((qd + c[r]) * swd);
            unsigned int pv = (unsigned int)__shfl_xor((int)v, 1, 64);
            if ((lane & 1) == 0) {
                unsigned int word = (v & 0xffffu) | (pv << 16);
                *(unsigned int*)&qt[tk * 1024 + d] = word;
            }
        }
    }
    __syncthreads();   // qt ready; NO MORE BARRIERS below

    // ================= Phase B: wave-per-token, continuous-issue pipeline ==
    int bb    = t0 >> 11;
    int tloc0 = t0 & (T_DIM - 1);
    int tt0   = w * 4;

    // per-wave rotated row offsets (slot s -> row (s+w)&7)
    size_t ro0 = (size_t)((0 + w) & 7) * PSTRIDE;
    size_t ro1 = (size_t)((1 + w) & 7) * PSTRIDE;
    size_t ro2 = (size_t)((2 + w) & 7) * PSTRIDE;
    size_t ro3 = (size_t)((3 + w) & 7) * PSTRIDE;
    size_t ro4 = (size_t)((4 + w) & 7) * PSTRIDE;
    size_t ro5 = (size_t)((5 + w) & 7) * PSTRIDE;
    size_t ro6 = (size_t)((6 + w) & 7) * PSTRIDE;
    size_t ro7 = (size_t)((7 + w) & 7) * PSTRIDE;

    const float* pb0 = prev + ((size_t)(bb * L_DIM) * T_DIM + (tloc0 + tt0)) * D_DIM + lane * 4;

    f32x4_t bufA[4], bufB[4];
    ISSUE(bufA, pb0 + ro0);

#pragma unroll 1
    for (int i = 0; i < 4; ++i) {
        int tt  = tt0 + i;
        int tok = t0 + tt;
        int t   = tloc0 + tt;
        const float* pbi = pb0 + (size_t)i * D_DIM;
        const float* pbn = pb0 + (size_t)(i < 3 ? i + 1 : i) * D_DIM;

        // q and h for this token
        f32x4_t h4[4], qv[4];
        const float* hb = h + (size_t)tok * D_DIM + lane * 4;
#pragma unroll
        for (int c = 0; c < 4; ++c) h4[c] = *(const f32x4_t*)(hb + c * 256);
#pragma unroll
        for (int c = 0; c < 4; ++c) {
            short4 qr = *(const short4*)&qt[tt * 1024 + c * 256 + lane * 4];
            qv[c].x = bf2f((unsigned short)qr.x);
            qv[c].y = bf2f((unsigned short)qr.y);
            qv[c].z = bf2f((unsigned short)qr.z);
            qv[c].w = bf2f((unsigned short)qr.w);
        }

        float ss[8], dt[8];
        unsigned int pw[8][8];

        ISSUE(bufB, pbi + ro1); PROC(0, bufA);
        ISSUE(bufA, pbi + ro2); PROC(1, bufB);
        ISSUE(bufB, pbi + ro3); PROC(2, bufA);
        ISSUE(bufA, pbi + ro4); PROC(3, bufB);
        ISSUE(bufB, pbi + ro5); PROC(4, bufA);
        ISSUE(bufA, pbi + ro6); PROC(5, bufB);
        ISSUE(bufB, pbi + ro7); PROC(6, bufA);
        ISSUE(bufA, pbn + ro0); PROC(7, bufB);   // prefetch next token row-slot0

        // token gate
        float tgp = 0.f;
#pragma unroll
        for (int c = 0; c < 4; ++c) {
            f32x4_t tw = *(const f32x4_t*)(tg_w + c * 256 + lane * 4);
            tgp += dot4v(h4[c], tw);
        }

        // 17 butterflies (6 levels)
#pragma unroll
        for (int off = 32; off; off >>= 1) {
#pragma unroll
            for (int l = 0; l < 8; ++l) {
                ss[l] += __shfl_xor(ss[l], off, 64);
                dt[l] += __shfl_xor(dt[l], off, 64);
            }
            tgp += __shfl_xor(tgp, off, 64);
        }

        float al[8], mx = -1e30f;
#pragma unroll
        for (int l = 0; l < 8; ++l) {
            al[l] = dt[l] * rsqrtf(ss[l] * (1.f / D_DIM) + EPSF);
            mx = fmaxf(mx, al[l]);
        }
        float asum = 0.f;
#pragma unroll
        for (int l = 0; l < 8; ++l) { al[l] = __expf(al[l] - mx); asum += al[l]; }
        float inv = 1.f / asum;
#pragma unroll
        for (int l = 0; l < 8; ++l) al[l] *= inv;

        float g = gate[0] / (1.f + __expf(-(tgp + tg_b[0])));

        // delta from bf16-packed rows
        f32x4_t dl[4];
#pragma unroll
        for (int c = 0; c < 4; ++c) { dl[c].x = 0.f; dl[c].y = 0.f; dl[c].z = 0.f; dl[c].w = 0.f; }
#pragma unroll
        for (int l = 0; l < 8; ++l) {
            float a = al[l];
#pragma unroll
            for (int c = 0; c < 4; ++c) {
                unsigned int w0 = pw[l][2 * c], w1 = pw[l][2 * c + 1];
                dl[c].x += a * lo2f(w0);
                dl[c].y += a * hi2f(w0);
                dl[c].z += a * lo2f(w1);
                dl[c].w += a * hi2f(w1);
            }
        }

        float dss = 0.f;
#pragma unroll
        for (int c = 0; c < 4; ++c) dss += dot4v(dl[c], dl[c]);
#pragma unroll
        for (int off = 32; off; off >>= 1) dss += __shfl_xor(dss, off, 64);
        float dscale = rsqrtf(dss * (1.f / D_DIM) + EPSF);

        float* ob = out + (size_t)tok * D_DIM + lane * 4;
#pragma unroll
        for (int c = 0; c < 4; ++c) {
            f32x4_t ow = *(const f32x4_t*)(out_w + c * 256 + lane * 4);
            f32x4_t o;
            o.x = h4[c].x + g * dl[c].x * dscale * ow.x;
            o.y = h4[c].y + g * dl[c].y * dscale * ow.y;
            o.z = h4[c].z + g * dl[c].z * dscale * ow.z;
            o.w = h4[c].w + g * dl[c].w * dscale * ow.w;
            __builtin_nontemporal_store(o, (f32x4_t*)(ob + c * 256));
        }

        if (lane < L_DIM)
            alpha_out[(size_t)bb * (L_DIM * T_DIM) +
                      (size_t)((lane + w) & 7) * T_DIM + t] = al[lane];
    }
}

extern "C" void kernel_launch(void* const* d_in, const int* in_sizes, int n_in,
                              void* d_out, int out_size, void* d_ws, size_t ws_size,
                              hipStream_t stream) {
    (void)in_sizes; (void)n_in; (void)out_size; (void)d_ws; (void)ws_size;
    const float* h       = (const float*)d_in[0];
    const float* prev    = (const float*)d_in[1];
    const float* query   = (const float*)d_in[2];
    const float* gate    = (const float*)d_in[3];
    const float* score_w = (const float*)d_in[4];
    const float* out_w   = (const float*)d_in[5];
    const float* qnw     = (const float*)d_in[6];
    const float* Wd      = (const float*)d_in[7];
    const float* Wu      = (const float*)d_in[8];
    const float* tg_w    = (const float*)d_in[9];
    const float* tg_b    = (const float*)d_in[10];

    float* out   = (float*)d_out;
    float* alpha = out + OUT_ELEMS;

    k_all<<<TOKS / 32, 512, 0, stream>>>(h, prev, query, score_w, out_w, tg_w,
                                         gate, tg_b, qnw, Wd, Wu, out, alpha);
}

// Round 13
// 79.494 us; speedup vs baseline: 1.1712x; 1.1712x over previous
//
#include <hip/hip_runtime.h>
#include <hip/hip_bf16.h>

#define D_DIM 1024
#define L_DIM 8
#define T_DIM 2048
#define B_DIM 4
#define TOKS  (B_DIM * T_DIM)                 // 8192
#define OUT_ELEMS ((size_t)TOKS * D_DIM)      // 8388608
#define EPSF 1e-6f

typedef __attribute__((ext_vector_type(8)))  short short8_t;
typedef __attribute__((ext_vector_type(16))) float f32x16_t;
typedef __attribute__((ext_vector_type(4)))  float f32x4_t;

__device__ __forceinline__ float dot4v(const f32x4_t& a, const f32x4_t& b) {
    return a.x * b.x + a.y * b.y + a.z * b.z + a.w * b.w;
}

__device__ __forceinline__ unsigned short f2bf(float f) {
    union { __hip_bfloat16 h; unsigned short u; } x;
    x.h = __float2bfloat16(f);
    return x.u;
}

__device__ __forceinline__ float bf2f(unsigned short u) {
    union { unsigned int i; float f; } x;
    x.i = ((unsigned int)u) << 16;
    return x.f;
}

__device__ __forceinline__ float lo2f(unsigned int u) {
    union { unsigned int i; float f; } x;
    x.i = u << 16;
    return x.f;
}

__device__ __forceinline__ float hi2f(unsigned int u) {
    union { unsigned int i; float f; } x;
    x.i = u & 0xffff0000u;
    return x.f;
}

// ---------------------------------------------------------------------------
// Single fused kernel. 256 blocks x 512 threads; block = 32 tokens.
// Phase A: q tile via MFMA GEMM1/GEMM2 -> qt LDS (bf16); h tile stashed to
//   LDS as bf16 (swizzled) during GEMM1; token-gate dot folded into the same
//   f32 h pass (g_sh).
// Phase B: wave-per-token x4, zero barriers, 32-deep load burst per token
//   (R11 structure, known good); h + q + g all from LDS; nt out store.
// ---------------------------------------------------------------------------
__global__ __launch_bounds__(512) void k_all(const float* __restrict__ h,
                                             const float* __restrict__ prev,
                                             const float* __restrict__ query,
                                             const float* __restrict__ score_w,
                                             const float* __restrict__ out_w,
                                             const float* __restrict__ tg_w,
                                             const float* __restrict__ gate,
                                             const float* __restrict__ tg_b,
                                             const float* __restrict__ qnw,
                                             const float* __restrict__ Wd,
                                             const float* __restrict__ Wu,
                                             float* __restrict__ out,
                                             float* __restrict__ alpha_out) {
    __shared__ __align__(16) char smem[65536];                 // c_red | qt overlay
    float (*c_red)[2][16][64] = (float (*)[2][16][64])smem;    // 64 KB
    unsigned short* qt = (unsigned short*)smem;                // 32 x 1024 bf16

    __shared__ __align__(16) char h_lds[65536];                // 32 x 1024 bf16 (swz)
    __shared__ float ssq_red[8][32];
    __shared__ float tg_red[8][32];
    __shared__ float scale_sh[32];
    __shared__ float g_sh[32];
    __shared__ unsigned short r_sw[2048];

    int tid  = threadIdx.x;
    int w    = tid >> 6;
    int lane = tid & 63;
    int t0   = blockIdx.x * 32;

    // ================= Phase A: GEMM1 (+ h stash + tg dot) =================
    f32x16_t acc0, acc1;
#pragma unroll
    for (int r = 0; r < 16; ++r) { acc0[r] = 0.f; acc1[r] = 0.f; }

    int arow = lane & 31;
    int koff = w * 128 + (lane >> 5) * 8;
    const float* hrow = h + (size_t)(t0 + arow) * D_DIM + koff;
    const float* w0r  = Wd + (size_t)arow * D_DIM + koff;
    const float* w1r  = Wd + (size_t)(32 + arow) * D_DIM + koff;
    const float* nr   = qnw + koff;
    const float* tgr  = tg_w + koff;

    // per-lane h_lds byte base (col part): w*256 + (lane>>5)*16
    int hcb = w * 256 + (lane >> 5) * 16;

    float ssqa = 0.f, tgp = 0.f;
#pragma unroll
    for (int s = 0; s < 8; ++s) {
        f32x4_t ha = *(const f32x4_t*)(hrow + s * 16);
        f32x4_t hb = *(const f32x4_t*)(hrow + s * 16 + 4);
        ssqa += dot4v(ha, ha) + dot4v(hb, hb);
        f32x4_t ta = *(const f32x4_t*)(tgr + s * 16);
        f32x4_t tb = *(const f32x4_t*)(tgr + s * 16 + 4);
        tgp += dot4v(ha, ta) + dot4v(hb, tb);
        short8_t af;
        af[0] = (short)f2bf(ha.x); af[1] = (short)f2bf(ha.y);
        af[2] = (short)f2bf(ha.z); af[3] = (short)f2bf(ha.w);
        af[4] = (short)f2bf(hb.x); af[5] = (short)f2bf(hb.y);
        af[6] = (short)f2bf(hb.z); af[7] = (short)f2bf(hb.w);
        // stash h tile (bf16, XOR-swizzled 16B slots)
        int hbyte = (arow * 2048 + hcb + s * 32) ^ ((arow & 7) << 4);
        *(short8_t*)(h_lds + hbyte) = af;
        f32x4_t na = *(const f32x4_t*)(nr + s * 16);
        f32x4_t nb = *(const f32x4_t*)(nr + s * 16 + 4);
        f32x4_t wa = *(const f32x4_t*)(w0r + s * 16);
        f32x4_t wb = *(const f32x4_t*)(w0r + s * 16 + 4);
        short8_t bf0;
        bf0[0] = (short)f2bf(wa.x * na.x); bf0[1] = (short)f2bf(wa.y * na.y);
        bf0[2] = (short)f2bf(wa.z * na.z); bf0[3] = (short)f2bf(wa.w * na.w);
        bf0[4] = (short)f2bf(wb.x * nb.x); bf0[5] = (short)f2bf(wb.y * nb.y);
        bf0[6] = (short)f2bf(wb.z * nb.z); bf0[7] = (short)f2bf(wb.w * nb.w);
        f32x4_t va = *(const f32x4_t*)(w1r + s * 16);
        f32x4_t vb = *(const f32x4_t*)(w1r + s * 16 + 4);
        short8_t bf1;
        bf1[0] = (short)f2bf(va.x * na.x); bf1[1] = (short)f2bf(va.y * na.y);
        bf1[2] = (short)f2bf(va.z * na.z); bf1[3] = (short)f2bf(va.w * na.w);
        bf1[4] = (short)f2bf(vb.x * nb.x); bf1[5] = (short)f2bf(vb.y * nb.y);
        bf1[6] = (short)f2bf(vb.z * nb.z); bf1[7] = (short)f2bf(vb.w * nb.w);
        acc0 = __builtin_amdgcn_mfma_f32_32x32x16_bf16(af, bf0, acc0, 0, 0, 0);
        acc1 = __builtin_amdgcn_mfma_f32_32x32x16_bf16(af, bf1, acc1, 0, 0, 0);
    }

    ssqa += __shfl_xor(ssqa, 32, 64);
    tgp  += __shfl_xor(tgp, 32, 64);
    if (lane < 32) { ssq_red[w][lane] = ssqa; tg_red[w][lane] = tgp; }
#pragma unroll
    for (int r = 0; r < 16; ++r) {
        c_red[w][0][r][lane] = acc0[r];
        c_red[w][1][r][lane] = acc1[r];
    }
    __syncthreads();

    if (tid < 32) {
        float s8 = 0.f, t8 = 0.f;
#pragma unroll
        for (int u = 0; u < 8; ++u) { s8 += ssq_red[u][tid]; t8 += tg_red[u][tid]; }
        scale_sh[tid] = rsqrtf(s8 * (1.f / D_DIM) + EPSF);
        g_sh[tid] = gate[0] / (1.f + __expf(-(t8 + tg_b[0])));
    }
    __syncthreads();

    for (int idx = tid; idx < 2048; idx += 512) {
        int nj = idx >> 10, rem = idx & 1023, reg = rem >> 6, ln = rem & 63;
        float v = 0.f;
#pragma unroll
        for (int u = 0; u < 8; ++u) v += c_red[u][nj][reg][ln];
        int tk = (reg & 3) + 8 * (reg >> 2) + 4 * (ln >> 5);
        int j  = nj * 32 + (ln & 31);
        v *= scale_sh[tk];
        int byte = (tk * 128 + j * 2) ^ ((tk & 7) << 4);
        r_sw[byte >> 1] = f2bf(v);
    }
    __syncthreads();

    // ================= Phase A: GEMM2 -> qt =================
    short8_t afr[4];
#pragma unroll
    for (int s = 0; s < 4; ++s) {
        int tk = lane & 31;
        int k  = s * 16 + (lane >> 5) * 8;
        int byte = (tk * 128 + k * 2) ^ ((tk & 7) << 4);
        afr[s] = *(const short8_t*)(&r_sw[byte >> 1]);
    }
    __syncthreads();   // c_red dead -> qt overlay safe

#pragma unroll
    for (int i = 0; i < 4; ++i) {
        int n0 = (w * 4 + i) * 32;
        int d  = n0 + (lane & 31);
        f32x16_t c;
#pragma unroll
        for (int r = 0; r < 16; ++r) c[r] = 0.f;
        const float* wup = Wu + (size_t)d * 64 + (lane >> 5) * 8;
#pragma unroll
        for (int s = 0; s < 4; ++s) {
            f32x4_t ua = *(const f32x4_t*)(wup + s * 16);
            f32x4_t ub = *(const f32x4_t*)(wup + s * 16 + 4);
            short8_t bf;
            bf[0] = (short)f2bf(ua.x); bf[1] = (short)f2bf(ua.y);
            bf[2] = (short)f2bf(ua.z); bf[3] = (short)f2bf(ua.w);
            bf[4] = (short)f2bf(ub.x); bf[5] = (short)f2bf(ub.y);
            bf[6] = (short)f2bf(ub.z); bf[7] = (short)f2bf(ub.w);
            c = __builtin_amdgcn_mfma_f32_32x32x16_bf16(afr[s], bf, c, 0, 0, 0);
        }
        float qd  = query[d];
        float swd = score_w[d];
#pragma unroll
        for (int r = 0; r < 16; ++r) {
            int tk = (r & 3) + 8 * (r >> 2) + 4 * (lane >> 5);
            unsigned int v = f2bf((qd + c[r]) * swd);
            unsigned int pv = (unsigned int)__shfl_xor((int)v, 1, 64);
            if ((lane & 1) == 0) {
                unsigned int word = (v & 0xffffu) | (pv << 16);
                *(unsigned int*)&qt[tk * 1024 + d] = word;
            }
        }
    }
    __syncthreads();   // qt + h_lds + g_sh ready; NO MORE BARRIERS below

    // ================= Phase B: wave-per-token, zero barriers =============
    int bb    = t0 >> 11;
    int tloc0 = t0 & (T_DIM - 1);

#pragma unroll 1
    for (int i = 0; i < 4; ++i) {
        int tt  = w * 4 + i;              // local token 0..31
        int tok = t0 + tt;
        int t   = tloc0 + tt;

        const float* pb = prev + ((size_t)(bb * L_DIM) * T_DIM + t) * D_DIM + lane * 4;
        f32x4_t p[L_DIM][4];
#pragma unroll
        for (int l = 0; l < L_DIM; ++l)
#pragma unroll
            for (int c = 0; c < 4; ++c)
                p[l][c] = *(const f32x4_t*)(pb + (size_t)l * T_DIM * D_DIM + c * 256);

        // h (bf16, from LDS, swizzled) and q (bf16, from qt)
        f32x4_t h4[4], qv[4];
#pragma unroll
        for (int c = 0; c < 4; ++c) {
            int rbyte = (tt * 2048 + c * 512 + lane * 8) ^ ((tt & 7) << 4);
            unsigned long long hq = *(const unsigned long long*)(h_lds + rbyte);
            unsigned int hw0 = (unsigned int)hq;
            unsigned int hw1 = (unsigned int)(hq >> 32);
            h4[c].x = lo2f(hw0); h4[c].y = hi2f(hw0);
            h4[c].z = lo2f(hw1); h4[c].w = hi2f(hw1);
        }
#pragma unroll
        for (int c = 0; c < 4; ++c) {
            short4 qr = *(const short4*)&qt[tt * 1024 + c * 256 + lane * 4];
            qv[c].x = bf2f((unsigned short)qr.x);
            qv[c].y = bf2f((unsigned short)qr.y);
            qv[c].z = bf2f((unsigned short)qr.z);
            qv[c].w = bf2f((unsigned short)qr.w);
        }

        float ss[L_DIM], dt[L_DIM];
#pragma unroll
        for (int l = 0; l < L_DIM; ++l) {
            float s = 0.f, d = 0.f;
#pragma unroll
            for (int c = 0; c < 4; ++c) {
                s += dot4v(p[l][c], p[l][c]);
                d += dot4v(p[l][c], qv[c]);
            }
            ss[l] = s; dt[l] = d;
        }

#pragma unroll
        for (int off = 32; off; off >>= 1) {
#pragma unroll
            for (int l = 0; l < L_DIM; ++l) {
                ss[l] += __shfl_xor(ss[l], off, 64);
                dt[l] += __shfl_xor(dt[l], off, 64);
            }
        }

        float al[L_DIM], mx = -1e30f;
#pragma unroll
        for (int l = 0; l < L_DIM; ++l) {
            al[l] = dt[l] * rsqrtf(ss[l] * (1.f / D_DIM) + EPSF);
            mx = fmaxf(mx, al[l]);
        }
        float asum = 0.f;
#pragma unroll
        for (int l = 0; l < L_DIM; ++l) { al[l] = __expf(al[l] - mx); asum += al[l]; }
        float inv = 1.f / asum;
#pragma unroll
        for (int l = 0; l < L_DIM; ++l) al[l] *= inv;

        float g = g_sh[tt];

        f32x4_t dl[4];
#pragma unroll
        for (int c = 0; c < 4; ++c) { dl[c].x = 0.f; dl[c].y = 0.f; dl[c].z = 0.f; dl[c].w = 0.f; }
#pragma unroll
        for (int l = 0; l < L_DIM; ++l)
#pragma unroll
            for (int c = 0; c < 4; ++c) {
                dl[c].x += al[l] * p[l][c].x;
                dl[c].y += al[l] * p[l][c].y;
                dl[c].z += al[l] * p[l][c].z;
                dl[c].w += al[l] * p[l][c].w;
            }

        float dss = 0.f;
#pragma unroll
        for (int c = 0; c < 4; ++c) dss += dot4v(dl[c], dl[c]);
#pragma unroll
        for (int off = 32; off; off >>= 1) dss += __shfl_xor(dss, off, 64);
        float dscale = rsqrtf(dss * (1.f / D_DIM) + EPSF);

        float* ob = out + (size_t)tok * D_DIM + lane * 4;
#pragma unroll
        for (int c = 0; c < 4; ++c) {
            f32x4_t ow = *(const f32x4_t*)(out_w + c * 256 + lane * 4);
            f32x4_t o;
            o.x = h4[c].x + g * dl[c].x * dscale * ow.x;
            o.y = h4[c].y + g * dl[c].y * dscale * ow.y;
            o.z = h4[c].z + g * dl[c].z * dscale * ow.z;
            o.w = h4[c].w + g * dl[c].w * dscale * ow.w;
            __builtin_nontemporal_store(o, (f32x4_t*)(ob + c * 256));
        }

        if (lane < L_DIM)
            alpha_out[(size_t)bb * (L_DIM * T_DIM) + (size_t)lane * T_DIM + t] = al[lane];
    }
}

extern "C" void kernel_launch(void* const* d_in, const int* in_sizes, int n_in,
                              void* d_out, int out_size, void* d_ws, size_t ws_size,
                              hipStream_t stream) {
    (void)in_sizes; (void)n_in; (void)out_size; (void)d_ws; (void)ws_size;
    const float* h       = (const float*)d_in[0];
    const float* prev    = (const float*)d_in[1];
    const float* query   = (const float*)d_in[2];
    const float* gate    = (const float*)d_in[3];
    const float* score_w = (const float*)d_in[4];
    const float* out_w   = (const float*)d_in[5];
    const float* qnw     = (const float*)d_in[6];
    const float* Wd      = (const float*)d_in[7];
    const float* Wu      = (const float*)d_in[8];
    const float* tg_w    = (const float*)d_in[9];
    const float* tg_b    = (const float*)d_in[10];

    float* out   = (float*)d_out;
    float* alpha = out + OUT_ELEMS;

    k_all<<<TOKS / 32, 512, 0, stream>>>(h, prev, query, score_w, out_w, tg_w,
                                         gate, tg_b, qnw, Wd, Wu, out, alpha);
}